// Round 1
// 389.831 us; speedup vs baseline: 1.1835x; 1.1835x over previous
//
#include <hip/hip_runtime.h>
#include <cstdint>
#include <cstddef>

typedef int i32x4 __attribute__((ext_vector_type(4)));

// ---------- prep: one launch quantizes x (per-row symmetric int8) and packs w ----------
//  blocks [0, xrows)   : x row b -> int8 + scale  (two passes over the 16KB row, 2nd is L1-hot)
//  blocks [xrows, ...) : w int32 -> int8, 4 ints -> 1 dword per thread, fully coalesced
__global__ __launch_bounds__(256) void prep_kernel(
    const float* __restrict__ x, signed char* __restrict__ xq, float* __restrict__ xs,
    const int* __restrict__ w, signed char* __restrict__ wq,
    int K, int xrows) {
  const int t = threadIdx.x;
  if ((int)blockIdx.x < xrows) {
    const int row = blockIdx.x;
    const float4* xr = (const float4*)(x + (size_t)row * K);
    const int n4 = K >> 2;
    float amax = 0.f;
    for (int i = t; i < n4; i += 256) {
      float4 v = xr[i];
      amax = fmaxf(amax, fmaxf(fmaxf(fabsf(v.x), fabsf(v.y)),
                               fmaxf(fabsf(v.z), fabsf(v.w))));
    }
#pragma unroll
    for (int off = 32; off > 0; off >>= 1)
      amax = fmaxf(amax, __shfl_xor(amax, off, 64));
    __shared__ float wmax[4];
    if ((t & 63) == 0) wmax[t >> 6] = amax;
    __syncthreads();
    amax = fmaxf(fmaxf(wmax[0], wmax[1]), fmaxf(wmax[2], wmax[3]));
    const float inv = (amax > 0.f) ? 127.f / amax : 0.f;
    if (t == 0) xs[row] = amax / 127.f;
    int* o = (int*)(xq + (size_t)row * K);
    for (int i = t; i < n4; i += 256) {
      float4 v = xr[i];                      // L1-hot re-read
      int a = __float2int_rn(v.x * inv) & 0xFF;
      int b = __float2int_rn(v.y * inv) & 0xFF;
      int c = __float2int_rn(v.z * inv) & 0xFF;
      int d = __float2int_rn(v.w * inv) & 0xFF;
      o[i] = a | (b << 8) | (c << 16) | (d << 24);
    }
  } else {
    const size_t g = (size_t)(blockIdx.x - xrows) * 256 + t;  // dword granule
    int4 v = ((const int4*)w)[g];
    ((int*)wq)[g] = (v.x & 0xFF) | ((v.y & 0xFF) << 8) |
                    ((v.z & 0xFF) << 16) | ((v.w & 0xFF) << 24);
  }
}

// ---------- async global->LDS, 16B per lane, wave-uniform LDS base ----------
static __device__ __forceinline__ void gld_lds16(const void* g, void* l) {
  __builtin_amdgcn_global_load_lds(
      (const __attribute__((address_space(1))) unsigned int*)g,
      (__attribute__((address_space(3))) unsigned int*)l,
      16, 0, 0);
}

// ---------- i8 NT GEMM, 256x256 tile, 8-phase counted-vmcnt schedule ----------
// C[m][n] = xs[m]*ws[n] * sum_k Aq[m][k]*Bq[n][k]
// 512 thr / 8 waves (2M x 4N), per-wave 128x64 out, BK=128 i8 (128B rows).
// LDS 128 KiB: [Abuf0][Abuf1][Bbuf0][Bbuf1] x 32KB, row-major 256x128B per tile,
// 16B chunks XOR-swizzled: lds chunk c holds global chunk c ^ (row&7)
// (linear LDS dest for global_load_lds; inverse swizzle on the per-lane
// global source; same XOR on the ds_read address -> conflict-free b128:
// every 8-lane group covers all 32 banks).
// Schedule: per K-tile 4 phases (mh,nh); each phase: {ds_read frags |
// issue one 8KB half-tile stage} -> s_barrier -> lgkmcnt(0) -> setprio(1)
// -> 16 MFMA -> setprio(0) -> [phase3: vmcnt(4)] -> s_barrier.
// Stage group G (2 loads) issued at global phase G-6; vmcnt(4) at phase 3
// leaves <=2 groups in flight and proves tile t+1 resident. Never drain
// vmcnt to 0 in the loop; raw s_barrier only (no __syncthreads drain).
// mfma_i32_16x16x64_i8 frag conventions identical to the verified 128^2
// kernel: A/B lane holds row (lane&15), k-chunk (lane>>4)*16B; C/D
// col=lane&15, row=(lane>>4)*4+reg. int32 dot exact: K*127^2 < 2^31.
__global__ __launch_bounds__(512, 2) void gemm_i8_8ph(
    const signed char* __restrict__ A,   // [M,K] i8
    const signed char* __restrict__ B,   // [N,K] i8
    const float* __restrict__ xs,        // [M] row scales
    const float* __restrict__ ws,        // [N] col scales
    float* __restrict__ C,               // [M,N] fp32
    int M, int N, int K) {
  __shared__ __align__(16) signed char lds[131072];

  const int tid  = threadIdx.x;
  const int lane = tid & 63;
  const int wave = tid >> 6;
  const int wm   = wave >> 2;          // 0..1
  const int wn   = wave & 3;           // 0..3
  const int q    = lane >> 4;          // 0..3 (16B k-chunk)
  const int r16  = lane & 15;
  const int e    = lane & 7;

  const int m0 = blockIdx.y << 8;
  const int n0 = blockIdx.x << 8;
  const int NT  = K >> 7;              // K-tiles of 128
  const int NT4 = NT << 2;             // stage groups total

  // ---- staging addressing: thread -> row tid>>3 (of 64), chunk tid&7,
  //      global chunk pre-swizzled so LDS stays linear for global_load_lds
  const int srow   = tid >> 3;
  const int schunk = ((tid & 7) ^ (srow & 7)) << 4;
  const signed char* sA = A + (size_t)(m0 + srow) * K + schunk;
  const signed char* sB = B + (size_t)(n0 + srow) * K + schunk;
  signed char* lW = lds + wave * 1024;  // wave-uniform LDS base

  // ---- reader offsets (M/N interleaved so phase regions = contiguous halves:
  //      A row = mt*32 + wm*16 + r16 ; B row = nh*128 + wn*32 + ntl*16 + r16)
  const int aro = ((wm << 4) + r16) << 7;      // A row base * 128
  const int bro = r16 << 7;                    // B row base * 128
  const int cs  = (q ^ e) << 4;                // swizzled chunk, kh0 (kh1 = ^64)

  i32x4 acc[8][4];
#pragma unroll
  for (int i = 0; i < 8; ++i)
#pragma unroll
    for (int j = 0; j < 4; ++j) acc[i][j] = (i32x4){0, 0, 0, 0};
  i32x4 af[4][2], bf[2][2];

// stage group G: tile G>>2, matrix G&1 (0=A,1=B), half (G>>1)&1 -> 2x 8KB loads
#define STAGE(Gv)                                                            \
  do {                                                                       \
    const int G_ = (Gv);                                                     \
    if (G_ < NT4) {                                                          \
      const int t_ = G_ >> 2;                                                \
      const int half_ = (G_ >> 1) & 1;                                       \
      signed char* l_ = lW + ((t_ & 1) << 15) + ((G_ & 1) << 16) +           \
                        (half_ << 14);                                       \
      const signed char* g_ = ((G_ & 1) ? sB : sA) +                         \
                              (size_t)(half_ << 7) * K + ((size_t)t_ << 7);  \
      gld_lds16(g_, l_);                                                     \
      gld_lds16(g_ + (size_t)64 * K, l_ + 8192);                             \
    }                                                                        \
  } while (0)

#define PHASE(MH, NH, READA, Gv, VMW)                                        \
  do {                                                                       \
    if (READA) {                                                             \
      _Pragma("unroll") for (int i_ = 0; i_ < 4; ++i_)                       \
        _Pragma("unroll") for (int kh_ = 0; kh_ < 2; ++kh_)                  \
          af[i_][kh_] = *(const i32x4*)(pA + ((((MH) << 2) + i_) << 12) +    \
                                        aro + (cs ^ (kh_ << 6)));            \
    }                                                                        \
    _Pragma("unroll") for (int j_ = 0; j_ < 2; ++j_)                         \
      _Pragma("unroll") for (int kh_ = 0; kh_ < 2; ++kh_)                    \
        bf[j_][kh_] = *(const i32x4*)(pB + ((NH) << 14) + (wn << 12) +       \
                                      (j_ << 11) + bro + (cs ^ (kh_ << 6))); \
    STAGE(Gv);                                                               \
    __builtin_amdgcn_s_barrier();                                            \
    asm volatile("s_waitcnt lgkmcnt(0)" ::: "memory");                       \
    __builtin_amdgcn_s_setprio(1);                                           \
    _Pragma("unroll") for (int kh_ = 0; kh_ < 2; ++kh_)                      \
      _Pragma("unroll") for (int i_ = 0; i_ < 4; ++i_)                       \
        _Pragma("unroll") for (int j_ = 0; j_ < 2; ++j_)                     \
          acc[((MH) << 2) + i_][((NH) << 1) + j_] =                          \
              __builtin_amdgcn_mfma_i32_16x16x64_i8(                         \
                  af[i_][kh_], bf[j_][kh_],                                  \
                  acc[((MH) << 2) + i_][((NH) << 1) + j_], 0, 0, 0);         \
    __builtin_amdgcn_s_setprio(0);                                           \
    if (VMW) asm volatile("s_waitcnt vmcnt(4)" ::: "memory");                \
    __builtin_amdgcn_s_barrier();                                            \
  } while (0)

  // prologue: tile0 (G0..3) + tile1 A0,B0 (G4,5); wait tile0 (<=4 loads left)
  STAGE(0); STAGE(1); STAGE(2); STAGE(3); STAGE(4); STAGE(5);
  asm volatile("s_waitcnt vmcnt(4)" ::: "memory");
  __builtin_amdgcn_s_barrier();

  for (int t = 0; t < NT; ++t) {
    const signed char* pA = lds + ((t & 1) << 15);
    const signed char* pB = lds + 65536 + ((t & 1) << 15);
    const int G0 = t << 2;
    PHASE(0, 0, 1, G0 + 6, 0);   // mh0,nh0: 8 A + 4 B reads, stage t+1.A1
    PHASE(0, 1, 0, G0 + 7, 0);   // mh0,nh1: 4 B reads,       stage t+1.B1
    PHASE(1, 0, 1, G0 + 8, 0);   // mh1,nh0: 8 A + 4 B reads, stage t+2.A0
    PHASE(1, 1, 0, G0 + 9, 1);   // mh1,nh1: 4 B reads, stage t+2.B0, vmcnt(4)
  }
#undef PHASE
#undef STAGE

  // epilogue: C/D col=lane&15, row=(lane>>4)*4+reg; out = acc * xs[row] * ws[col]
#pragma unroll
  for (int mt = 0; mt < 8; ++mt) {
    const int row0 = m0 + (mt << 5) + (wm << 4) + (q << 2);
    float xv[4];
#pragma unroll
    for (int r = 0; r < 4; ++r) xv[r] = xs[row0 + r];
#pragma unroll
    for (int nt = 0; nt < 4; ++nt) {
      const int col = n0 + ((nt >> 1) << 7) + (wn << 5) + ((nt & 1) << 4) + r16;
      const float s = ws[col];
      float* Cp = C + (size_t)row0 * N + col;
#pragma unroll
      for (int r = 0; r < 4; ++r)
        Cp[(size_t)r * N] = (float)acc[mt][nt][r] * xv[r] * s;
    }
  }
}

// ---------- fallback (odd shapes) ----------
__global__ void naive_kernel(const float* __restrict__ x, const int* __restrict__ w,
                             const float* __restrict__ sc, float* __restrict__ out,
                             int M, int N, int K) {
  int idx = blockIdx.x * 256 + threadIdx.x;
  if (idx >= M * N) return;
  int m = idx / N, n = idx % N;
  const float* xr = x + (size_t)m * K;
  const int*   wr = w + (size_t)n * K;
  float acc = 0.f;
  for (int k = 0; k < K; ++k) acc += xr[k] * (float)wr[k];
  out[idx] = acc * sc[n];
}

extern "C" void kernel_launch(void* const* d_in, const int* in_sizes, int n_in,
                              void* d_out, int out_size, void* d_ws, size_t ws_size,
                              hipStream_t stream) {
  const float* x  = (const float*)d_in[0];
  const int*   w  = (const int*)d_in[1];
  const float* sc = (const float*)d_in[2];
  float* out = (float*)d_out;

  const int N = in_sizes[2];          // D_OUT
  const int K = in_sizes[1] / N;      // D_IN
  const int M = in_sizes[0] / K;      // B*S

  const size_t need = (size_t)M * K + (size_t)N * K + (size_t)M * 4 + 16;
  if (ws_size < need || (M & 255) || (N & 255) || (K & 127) || K < 256 ||
      (((size_t)N * K) % 1024)) {
    int total = M * N;
    naive_kernel<<<(total + 255) / 256, 256, 0, stream>>>(x, w, sc, out, M, N, K);
    return;
  }

  signed char* xq = (signed char*)d_ws;
  signed char* wq = xq + (size_t)M * K;
  float*       xsc = (float*)(wq + (size_t)N * K);

  const int wblocks = (int)(((size_t)N * K) / 1024);  // 4 ints/thread
  prep_kernel<<<M + wblocks, 256, 0, stream>>>(x, xq, xsc, w, wq, K, M);

  dim3 grid(N >> 8, M >> 8);
  gemm_i8_8ph<<<grid, 512, 0, stream>>>(xq, wq, xsc, sc, out, M, N, K);
}

// Round 2
// 383.624 us; speedup vs baseline: 1.2026x; 1.0162x over previous
//
#include <hip/hip_runtime.h>
#include <cstdint>
#include <cstddef>

typedef int i32x4 __attribute__((ext_vector_type(4)));

static __device__ __forceinline__ int pack4(float4 v, float inv) {
  int a = __float2int_rn(v.x * inv) & 0xFF;
  int b = __float2int_rn(v.y * inv) & 0xFF;
  int c = __float2int_rn(v.z * inv) & 0xFF;
  int d = __float2int_rn(v.w * inv) & 0xFF;
  return a | (b << 8) | (c << 16) | (d << 24);
}

// ---------- prep: quantize x rows (per-row symmetric int8) + pack w ----------
// x fast path (K==4096): the whole row lives in registers (4 float4/thread),
// ONE HBM read (round-1's "L1-hot" re-read was really L2/HBM: resident rows
// >> 4MB L2 -> prep ran at 1.6 TB/s). w path: 16B/lane read, 4B/lane write,
// fully coalesced, unchanged.
__global__ __launch_bounds__(256) void prep_kernel(
    const float* __restrict__ x, signed char* __restrict__ xq, float* __restrict__ xs,
    const int* __restrict__ w, signed char* __restrict__ wq,
    int K, int xrows) {
  const int t = threadIdx.x;
  if ((int)blockIdx.x < xrows) {
    const int row = blockIdx.x;
    const float4* xr = (const float4*)(x + (size_t)row * K);
    const int n4 = K >> 2;
    __shared__ float wmax[4];
    if (n4 == 1024) {
      // K==4096: single-pass, row in registers
      float4 v0 = xr[t], v1 = xr[t + 256], v2 = xr[t + 512], v3 = xr[t + 768];
      float amax = fmaxf(fmaxf(fabsf(v0.x), fabsf(v0.y)),
                         fmaxf(fabsf(v0.z), fabsf(v0.w)));
      amax = fmaxf(amax, fmaxf(fmaxf(fabsf(v1.x), fabsf(v1.y)),
                               fmaxf(fabsf(v1.z), fabsf(v1.w))));
      amax = fmaxf(amax, fmaxf(fmaxf(fabsf(v2.x), fabsf(v2.y)),
                               fmaxf(fabsf(v2.z), fabsf(v2.w))));
      amax = fmaxf(amax, fmaxf(fmaxf(fabsf(v3.x), fabsf(v3.y)),
                               fmaxf(fabsf(v3.z), fabsf(v3.w))));
#pragma unroll
      for (int off = 32; off > 0; off >>= 1)
        amax = fmaxf(amax, __shfl_xor(amax, off, 64));
      if ((t & 63) == 0) wmax[t >> 6] = amax;
      __syncthreads();
      amax = fmaxf(fmaxf(wmax[0], wmax[1]), fmaxf(wmax[2], wmax[3]));
      const float inv = (amax > 0.f) ? 127.f / amax : 0.f;
      if (t == 0) xs[row] = amax / 127.f;
      int* o = (int*)(xq + (size_t)row * K);
      o[t]       = pack4(v0, inv);
      o[t + 256] = pack4(v1, inv);
      o[t + 512] = pack4(v2, inv);
      o[t + 768] = pack4(v3, inv);
    } else {
      // general K: two-pass (fallback, unused at this shape)
      float amax = 0.f;
      for (int i = t; i < n4; i += 256) {
        float4 v = xr[i];
        amax = fmaxf(amax, fmaxf(fmaxf(fabsf(v.x), fabsf(v.y)),
                                 fmaxf(fabsf(v.z), fabsf(v.w))));
      }
#pragma unroll
      for (int off = 32; off > 0; off >>= 1)
        amax = fmaxf(amax, __shfl_xor(amax, off, 64));
      if ((t & 63) == 0) wmax[t >> 6] = amax;
      __syncthreads();
      amax = fmaxf(fmaxf(wmax[0], wmax[1]), fmaxf(wmax[2], wmax[3]));
      const float inv = (amax > 0.f) ? 127.f / amax : 0.f;
      if (t == 0) xs[row] = amax / 127.f;
      int* o = (int*)(xq + (size_t)row * K);
      for (int i = t; i < n4; i += 256) {
        float4 v = xr[i];
        o[i] = pack4(v, inv);
      }
    }
  } else {
    const size_t g = (size_t)(blockIdx.x - xrows) * 256 + t;  // dword granule
    int4 v = ((const int4*)w)[g];
    ((int*)wq)[g] = (v.x & 0xFF) | ((v.y & 0xFF) << 8) |
                    ((v.z & 0xFF) << 16) | ((v.w & 0xFF) << 24);
  }
}

// ---------- async global->LDS, 16B per lane, wave-uniform LDS base ----------
static __device__ __forceinline__ void gld_lds16(const void* g, void* l) {
  __builtin_amdgcn_global_load_lds(
      (const __attribute__((address_space(1))) unsigned int*)g,
      (__attribute__((address_space(3))) unsigned int*)l,
      16, 0, 0);
}

// ---------- i8 NT GEMM, 256x256 tile, 2-phase/K-tile counted-vmcnt schedule ----------
// C[m][n] = xs[m]*ws[n] * sum_k Aq[m][k]*Bq[n][k]
// 512 thr / 8 waves (2M x 4N), per-wave 128x64 out, BK=128 i8 (128B rows).
// LDS 128 KiB: [Abuf0][Abuf1][Bbuf0][Bbuf1] x 32KB; 16B chunks XOR-swizzled
// (linear LDS dest for global_load_lds, inverse swizzle on per-lane global
// source, same XOR on ds_read -> 2-way max = conflict-free, measured 0).
//
// i8 MFMA does 2xK per inst, so round-1's 16-MFMA phases paid the template's
// per-barrier overhead for HALF the compute. This version: 2 phases per
// K-tile, 32 MFMA per barrier, B fragments held in regs across the tile
// (B read from LDS ONCE/tile -> 192KB LDS/CU/tile < 2612cy MFMA floor).
//   phaseA(t): ds_read A-half0(8 b128) + all B(8 b128); stage t+1.{A1,B1};
//              barrier; lgkm0; 32 MFMA (mh0); barrier.
//   phaseB(t): ds_read A-half1(8);      stage t+2.{A0,B0};
//              barrier; lgkm0; 32 MFMA (mh1); vmcnt; barrier.
// Stage-safety (write region R of buf[t&1] only after R's last tile-t read
// completed + barrier): A0,B0,B1 last read in phaseA(t) -> stageable from
// phaseB(t); A1 last read in phaseB(t) -> stageable from phaseA(t+1). Both
// assignments above satisfy this (t+1 groups target buf[(t+1)&1], dead since
// t-1). vmcnt(4) at phaseB(t) end: outstanding = t+1.{A0,B0}(left), 
// t+1.{A1,B1}, t+2.{A0,B0} = 12 -> retire 8 oldest = ALL of tile t+1 before
// phaseA(t+1) reads it; 4 stay in flight (never drain mid-loop). Tail: at
// t>=NT-2 the t+2 stages are guarded out, so vmcnt(4) would no longer cover
// tile t+1 -> use vmcnt(0) there (fixes round-1's latent tail race).
// Frag conventions unchanged (verified): A/B lane = row(lane&15),
// k-chunk (lane>>4)*16B; C/D col=lane&15, row=(lane>>4)*4+reg. Exact int32.
__global__ __launch_bounds__(512, 2) void gemm_i8_2ph(
    const signed char* __restrict__ A,   // [M,K] i8
    const signed char* __restrict__ B,   // [N,K] i8
    const float* __restrict__ xs,        // [M] row scales
    const float* __restrict__ ws,        // [N] col scales
    float* __restrict__ C,               // [M,N] fp32
    int M, int N, int K) {
  __shared__ __align__(16) signed char lds[131072];

  const int tid  = threadIdx.x;
  const int lane = tid & 63;
  const int wave = tid >> 6;
  const int wm   = wave >> 2;          // 0..1
  const int wn   = wave & 3;           // 0..3
  const int q    = lane >> 4;          // 0..3 (16B k-chunk)
  const int r16  = lane & 15;
  const int e    = lane & 7;

  // bijective XCD swizzle (nwg = 512 = 8*64 exact; guarded for generality)
  const unsigned nwg = gridDim.x * gridDim.y;
  unsigned id = blockIdx.y * gridDim.x + blockIdx.x;
  if ((nwg & 7u) == 0u) id = (id & 7u) * (nwg >> 3) + (id >> 3);
  const int m0 = (int)(id / gridDim.x) << 8;
  const int n0 = (int)(id % gridDim.x) << 8;

  const int NT = K >> 7;               // K-tiles of 128

  // staging: thread -> row tid>>3 (of 64), chunk tid&7, global pre-swizzled
  const int srow   = tid >> 3;
  const int schunk = ((tid & 7) ^ (srow & 7)) << 4;
  const signed char* sA = A + (size_t)(m0 + srow) * K + schunk;
  const signed char* sB = B + (size_t)(n0 + srow) * K + schunk;
  signed char* lW = lds + wave * 1024;  // wave-uniform LDS base

  // reader offsets: A row = mt*32 + wm*16 + r16 ; B row = nh*128+wn*32+j*16+r16
  const int aro = ((wm << 4) + r16) << 7;
  const int bro = r16 << 7;
  const int cs  = (q ^ e) << 4;        // swizzled chunk, kh0 (kh1 = ^64)

  i32x4 acc[8][4];
#pragma unroll
  for (int i = 0; i < 8; ++i)
#pragma unroll
    for (int j = 0; j < 4; ++j) acc[i][j] = (i32x4){0, 0, 0, 0};
  i32x4 af[4][2], bf[2][2][2];

// stage group g of tile Tv: g 0=A-half0 1=B-half0 2=A-half1 3=B-half1
#define STAGE(Tv, Gv)                                                        \
  do {                                                                       \
    const int t_ = (Tv);                                                     \
    if (t_ < NT) {                                                           \
      const int mat_ = (Gv) & 1, half_ = (Gv) >> 1;                          \
      signed char* l_ = lW + ((t_ & 1) << 15) + (mat_ << 16) + (half_ << 14);\
      const signed char* g_ = (mat_ ? sB : sA) +                             \
                              (size_t)(half_ << 7) * K + ((size_t)t_ << 7);  \
      gld_lds16(g_, l_);                                                     \
      gld_lds16(g_ + (size_t)64 * K, l_ + 8192);                             \
    }                                                                        \
  } while (0)

#define READ_A(MH)                                                           \
  _Pragma("unroll") for (int i_ = 0; i_ < 4; ++i_)                           \
    _Pragma("unroll") for (int kh_ = 0; kh_ < 2; ++kh_)                      \
      af[i_][kh_] = *(const i32x4*)(pA + ((((MH) << 2) + i_) << 12) + aro +  \
                                    (cs ^ (kh_ << 6)));

#define READ_B                                                               \
  _Pragma("unroll") for (int nh_ = 0; nh_ < 2; ++nh_)                        \
    _Pragma("unroll") for (int j_ = 0; j_ < 2; ++j_)                         \
      _Pragma("unroll") for (int kh_ = 0; kh_ < 2; ++kh_)                    \
        bf[nh_][j_][kh_] = *(const i32x4*)(pB + (nh_ << 14) + (wn << 12) +   \
                                           (j_ << 11) + bro + (cs ^ (kh_ << 6)));

#define MFMA_HALF(MH)                                                        \
  __builtin_amdgcn_s_setprio(1);                                             \
  _Pragma("unroll") for (int kh_ = 0; kh_ < 2; ++kh_)                        \
    _Pragma("unroll") for (int i_ = 0; i_ < 4; ++i_)                         \
      _Pragma("unroll") for (int nh_ = 0; nh_ < 2; ++nh_)                    \
        _Pragma("unroll") for (int j_ = 0; j_ < 2; ++j_)                     \
          acc[((MH) << 2) + i_][(nh_ << 1) + j_] =                           \
              __builtin_amdgcn_mfma_i32_16x16x64_i8(                         \
                  af[i_][kh_], bf[nh_][j_][kh_],                             \
                  acc[((MH) << 2) + i_][(nh_ << 1) + j_], 0, 0, 0);          \
  __builtin_amdgcn_s_setprio(0);

  // prologue: tile0 all + tile1 {A0,B0}; vmcnt(4) retires the 8 tile0 loads
  STAGE(0, 0); STAGE(0, 1); STAGE(0, 2); STAGE(0, 3);
  STAGE(1, 0); STAGE(1, 1);
  asm volatile("s_waitcnt vmcnt(4)" ::: "memory");
  __builtin_amdgcn_s_barrier();

  for (int t = 0; t < NT; ++t) {
    const signed char* pA = lds + ((t & 1) << 15);
    const signed char* pB = lds + 65536 + ((t & 1) << 15);
    // ---- phase A: mh0, read all B (held in regs for phase B)
    READ_A(0);
    READ_B;
    STAGE(t + 1, 2); STAGE(t + 1, 3);          // t+1.A1, t+1.B1
    __builtin_amdgcn_s_barrier();
    asm volatile("s_waitcnt lgkmcnt(0)" ::: "memory");
    MFMA_HALF(0);
    __builtin_amdgcn_s_barrier();
    // ---- phase B: mh1, B from regs
    READ_A(1);
    STAGE(t + 2, 0); STAGE(t + 2, 1);          // t+2.A0, t+2.B0
    __builtin_amdgcn_s_barrier();
    asm volatile("s_waitcnt lgkmcnt(0)" ::: "memory");
    MFMA_HALF(1);
    if (t < NT - 2) asm volatile("s_waitcnt vmcnt(4)" ::: "memory");
    else            asm volatile("s_waitcnt vmcnt(0)" ::: "memory");
    __builtin_amdgcn_s_barrier();
  }
#undef MFMA_HALF
#undef READ_B
#undef READ_A
#undef STAGE

  // epilogue: C/D col=lane&15, row=(lane>>4)*4+reg; out = acc*xs[row]*ws[col]
#pragma unroll
  for (int mt = 0; mt < 8; ++mt) {
    const int row0 = m0 + (mt << 5) + (wm << 4) + (q << 2);
    float xv[4];
#pragma unroll
    for (int r = 0; r < 4; ++r) xv[r] = xs[row0 + r];
#pragma unroll
    for (int nt = 0; nt < 4; ++nt) {
      const int col = n0 + ((nt >> 1) << 7) + (wn << 5) + ((nt & 1) << 4) + r16;
      const float s = ws[col];
      float* Cp = C + (size_t)row0 * N + col;
#pragma unroll
      for (int r = 0; r < 4; ++r)
        Cp[(size_t)r * N] = (float)acc[mt][nt][r] * xv[r] * s;
    }
  }
}

// ---------- fallback (odd shapes) ----------
__global__ void naive_kernel(const float* __restrict__ x, const int* __restrict__ w,
                             const float* __restrict__ sc, float* __restrict__ out,
                             int M, int N, int K) {
  int idx = blockIdx.x * 256 + threadIdx.x;
  if (idx >= M * N) return;
  int m = idx / N, n = idx % N;
  const float* xr = x + (size_t)m * K;
  const int*   wr = w + (size_t)n * K;
  float acc = 0.f;
  for (int k = 0; k < K; ++k) acc += xr[k] * (float)wr[k];
  out[idx] = acc * sc[n];
}

extern "C" void kernel_launch(void* const* d_in, const int* in_sizes, int n_in,
                              void* d_out, int out_size, void* d_ws, size_t ws_size,
                              hipStream_t stream) {
  const float* x  = (const float*)d_in[0];
  const int*   w  = (const int*)d_in[1];
  const float* sc = (const float*)d_in[2];
  float* out = (float*)d_out;

  const int N = in_sizes[2];          // D_OUT
  const int K = in_sizes[1] / N;      // D_IN
  const int M = in_sizes[0] / K;      // B*S

  const size_t need = (size_t)M * K + (size_t)N * K + (size_t)M * 4 + 16;
  if (ws_size < need || (M & 255) || (N & 255) || (K & 127) || K < 256 ||
      (((size_t)N * K) % 1024)) {
    int total = M * N;
    naive_kernel<<<(total + 255) / 256, 256, 0, stream>>>(x, w, sc, out, M, N, K);
    return;
  }

  signed char* xq = (signed char*)d_ws;
  signed char* wq = xq + (size_t)M * K;
  float*       xsc = (float*)(wq + (size_t)N * K);

  const int wblocks = (int)(((size_t)N * K) / 1024);  // 4 ints/thread
  prep_kernel<<<M + wblocks, 256, 0, stream>>>(x, xq, xsc, w, wq, K, M);

  dim3 grid(N >> 8, M >> 8);
  gemm_i8_2ph<<<grid, 512, 0, stream>>>(xq, wq, xsc, sc, out, M, N, K);
}